// Round 3
// baseline (118.608 us; speedup 1.0000x reference)
//
#include <hip/hip_runtime.h>
#include <hip/hip_cooperative_groups.h>
#include <stdint.h>

namespace cg = cooperative_groups;

// RBF layer as one bf16 GEMM, fused prep+GEMM in a single cooperative kernel.
//   A_cat[b] = [ x^2 (784) | x (784) | 1, 0..0 ]      (KC=1664, zero-padded)
//   B_cat[r] = [ w (784)   | -2*c*w (784) | t3, 0..0 ],  w = 1/s^2, t3 = sum c^2 w
//   out = exp(-0.5 * A_cat · B_cat^T)
// Phase 2: one 32x32 output tile per 256-thr block; K split 4-ways across waves
// (13 steps of 32 each) -> 2048 waves = 2/SIMD TLP; LDS reduce + exp epilogue.
// XCD-aligned: XCD x preps & reads A rows [256x,256x+256) -> local-L2 hits.

typedef unsigned short u16;
typedef u16   u16x8  __attribute__((ext_vector_type(8)));
typedef u16   u16x4  __attribute__((ext_vector_type(4)));
typedef __bf16 bf16x8 __attribute__((ext_vector_type(8)));
typedef float  f32x4  __attribute__((ext_vector_type(4)));

#define NB 2048
#define NR 256
#define ND 784
#define KC 1664   // 784 + 784 + 96 zero tail; 4 * 416
#define KW 416    // per-wave K slice = 13 steps of 32
#define NSTEP 13

__device__ __forceinline__ u16 f2bf(float f) {
    union { float f; uint32_t u; } v; v.f = f;
    uint32_t r = v.u + 0x7fffu + ((v.u >> 16) & 1u);  // RNE
    return (u16)(r >> 16);
}

__global__ __launch_bounds__(256, 2) void rbf_fused(
        const float* __restrict__ inputs, const float* __restrict__ centers,
        const float* __restrict__ sigmas, u16* __restrict__ Acat,
        u16* __restrict__ Bcat, float* __restrict__ out)
{
    const int w    = threadIdx.x >> 6;
    const int lane = threadIdx.x & 63;
    const int bid  = (int)blockIdx.x;
    const int xcd  = bid & 7;
    const int j    = bid >> 3;           // 0..63 within XCD

    // ================= phase 1: build bf16 panels =================
    {   // A row (one per wave; XCD x owns rows [256x, 256x+256))
        const int b = xcd * 256 + j * 4 + w;
        const float4* src = (const float4*)(inputs + (size_t)b * ND);
        float4 v0 = src[lane];
        float4 v1 = src[lane + 64];
        float4 v2 = src[lane + 128];
        float4 v3 = make_float4(0.f, 0.f, 0.f, 0.f);
        if (lane < 4) v3 = src[lane + 192];            // 784 = 4*(64+64+64+4)
        float ss = v0.x*v0.x + v0.y*v0.y + v0.z*v0.z + v0.w*v0.w
                 + v1.x*v1.x + v1.y*v1.y + v1.z*v1.z + v1.w*v1.w
                 + v2.x*v2.x + v2.y*v2.y + v2.z*v2.z + v2.w*v2.w
                 + v3.x*v3.x + v3.y*v3.y + v3.z*v3.z + v3.w*v3.w;
        #pragma unroll
        for (int m = 32; m; m >>= 1) ss += __shfl_xor(ss, m);
        const float inv = rsqrtf(fmaxf(ss, 1e-12f));
        u16* rowA = Acat + (size_t)b * KC;
        auto wrA = [&](int col, float4 v) {
            float x0 = v.x*inv, x1 = v.y*inv, x2 = v.z*inv, x3 = v.w*inv;
            u16x4 q2 = { f2bf(x0*x0), f2bf(x1*x1), f2bf(x2*x2), f2bf(x3*x3) };
            u16x4 q1 = { f2bf(x0),    f2bf(x1),    f2bf(x2),    f2bf(x3)    };
            *(u16x4*)(rowA + col)      = q2;
            *(u16x4*)(rowA + ND + col) = q1;
        };
        wrA(4*lane, v0);
        wrA(4*(lane+64), v1);
        wrA(4*(lane+128), v2);
        if (lane < 4) wrA(4*(lane+192), v3);
        if (lane < 24) {                               // tail cols [1568,1664)
            u16x4 t = {0,0,0,0};
            if (lane == 0) t.x = 0x3F80;               // bf16 1.0
            *(u16x4*)(rowA + 2*ND + 4*lane) = t;
        }
    }
    if (bid < 64) {   // B rows (4 per block, one per wave)
        const int r = bid * 4 + w;
        const float4* cp = (const float4*)(centers + (size_t)r * ND);
        const float4* sp = (const float4*)(sigmas  + (size_t)r * ND);
        u16* rowB = Bcat + (size_t)r * KC;
        float t3 = 0.f;
        auto wrB = [&](int col, float4 c, float4 s) {
            float w0 = 1.f/(s.x*s.x), w1 = 1.f/(s.y*s.y), w2 = 1.f/(s.z*s.z), w3 = 1.f/(s.w*s.w);
            float c0 = c.x*w0, c1 = c.y*w1, c2 = c.z*w2, c3 = c.w*w3;
            t3 += c.x*c0 + c.y*c1 + c.z*c2 + c.w*c3;
            u16x4 qw = { f2bf(w0), f2bf(w1), f2bf(w2), f2bf(w3) };
            u16x4 qm = { f2bf(-2.f*c0), f2bf(-2.f*c1), f2bf(-2.f*c2), f2bf(-2.f*c3) };
            *(u16x4*)(rowB + col)      = qw;
            *(u16x4*)(rowB + ND + col) = qm;
        };
        wrB(4*lane,       cp[lane],     sp[lane]);
        wrB(4*(lane+64),  cp[lane+64],  sp[lane+64]);
        wrB(4*(lane+128), cp[lane+128], sp[lane+128]);
        if (lane < 4) wrB(4*(lane+192), cp[lane+192], sp[lane+192]);
        #pragma unroll
        for (int m = 32; m; m >>= 1) t3 += __shfl_xor(t3, m);
        if (lane < 24) {
            u16x4 t = {0,0,0,0};
            if (lane == 0) t.x = f2bf(t3);
            *(u16x4*)(rowB + 2*ND + 4*lane) = t;
        }
    }

    __threadfence();
    cg::this_grid().sync();

    // ================= phase 2: 32x32 tile GEMM, K split across 4 waves =========
    const int rb = j >> 3, cb = j & 7;
    const int wm = xcd * 256 + rb * 32;   // batch rows (local-XCD A band)
    const int wn = cb * 32;               // center rows
    const int r16 = lane & 15;
    const int ko  = (lane >> 4) * 8;
    const int kb  = w * KW;

    const u16* a0p = Acat + (size_t)(wm + r16) * KC + ko + kb;
    const u16* a1p = a0p + 16 * KC;
    const u16* b0p = Bcat + (size_t)(wn + r16) * KC + ko + kb;
    const u16* b1p = b0p + 16 * KC;

    f32x4 acc00 = {0,0,0,0}, acc01 = {0,0,0,0}, acc10 = {0,0,0,0}, acc11 = {0,0,0,0};
    u16x8 a0[4], a1[4], b0[4], b1[4];

#define LDSET(J, KS) do { const int o_ = (KS) * 32;                           \
    a0[J] = *(const u16x8*)(a0p + o_); a1[J] = *(const u16x8*)(a1p + o_);     \
    b0[J] = *(const u16x8*)(b0p + o_); b1[J] = *(const u16x8*)(b1p + o_); } while (0)

#define MM(J) do {                                                                        \
    acc00 = __builtin_amdgcn_mfma_f32_16x16x32_bf16(__builtin_bit_cast(bf16x8, a0[J]),    \
                __builtin_bit_cast(bf16x8, b0[J]), acc00, 0, 0, 0);                       \
    acc01 = __builtin_amdgcn_mfma_f32_16x16x32_bf16(__builtin_bit_cast(bf16x8, a0[J]),    \
                __builtin_bit_cast(bf16x8, b1[J]), acc01, 0, 0, 0);                       \
    acc10 = __builtin_amdgcn_mfma_f32_16x16x32_bf16(__builtin_bit_cast(bf16x8, a1[J]),    \
                __builtin_bit_cast(bf16x8, b0[J]), acc10, 0, 0, 0);                       \
    acc11 = __builtin_amdgcn_mfma_f32_16x16x32_bf16(__builtin_bit_cast(bf16x8, a1[J]),    \
                __builtin_bit_cast(bf16x8, b1[J]), acc11, 0, 0, 0); } while (0)

    #pragma unroll
    for (int s = 0; s < 4; ++s) LDSET(s, s);
    #pragma unroll
    for (int s = 0; s < NSTEP; ++s) {       // fully unrolled: all indices static
        MM(s & 3);
        if (s + 4 < NSTEP) LDSET(s & 3, s + 4);
    }

    // ================= phase 3: cross-wave K-reduce + exp + store ===============
    __shared__ float red[4][16][64];
    #pragma unroll
    for (int q = 0; q < 4; ++q) {
        red[w][q     ][lane] = acc00[q];
        red[w][4 + q ][lane] = acc01[q];
        red[w][8 + q ][lane] = acc10[q];
        red[w][12 + q][lane] = acc11[q];
    }
    __syncthreads();
    // wave w owns quadrant w: MO=(w>>1)*16, NO=(w&1)*16
    {
        const int MO = (w >> 1) * 16, NO = (w & 1) * 16;
        const int row0 = wm + MO + ((lane >> 4) << 2);
        const int col  = wn + NO + (lane & 15);
        float* o_ = out + (size_t)row0 * NR + col;
        #pragma unroll
        for (int q = 0; q < 4; ++q) {
            float s = red[0][w*4 + q][lane] + red[1][w*4 + q][lane]
                    + red[2][w*4 + q][lane] + red[3][w*4 + q][lane];
            o_[q * NR] = __expf(-0.5f * s);
        }
    }
#undef LDSET
#undef MM
}

extern "C" void kernel_launch(void* const* d_in, const int* in_sizes, int n_in,
                              void* d_out, int out_size, void* d_ws, size_t ws_size,
                              hipStream_t stream) {
    const float* inputs  = (const float*)d_in[0];
    const float* centers = (const float*)d_in[1];
    const float* sigmas  = (const float*)d_in[2];
    u16* Acat = (u16*)d_ws;                       // 2048*1664*2 = 6.8 MB
    u16* Bcat = Acat + (size_t)NB * KC;           // + 256*1664*2 = 0.85 MB
    float* out = (float*)d_out;
    void* args[] = { (void*)&inputs, (void*)&centers, (void*)&sigmas,
                     (void*)&Acat, (void*)&Bcat, (void*)&out };
    hipLaunchCooperativeKernel((const void*)rbf_fused, dim3(512), dim3(256),
                               args, 0, stream);
}

// Round 4
// 25.069 us; speedup vs baseline: 4.7312x; 4.7312x over previous
//
#include <hip/hip_runtime.h>
#include <stdint.h>

// RBF layer: out[b,r] = exp(-0.5 * sum_d ((x[b,d]-c[r,d])^2 / s[r,d]^2)),
// x = l2_normalize(inputs).  Expanded to one bf16 GEMM with K=1664 (zero-padded):
//   A_cat[b] = [ x^2 (784) | x (784) | 1, 0..0 ]
//   B_cat[r] = [ w (784)   | -2*c*w (784) | t3, 0..0 ],  w = 1/s^2, t3 = sum c^2 w
//   out = exp(-0.5 * A_cat · B_cat^T)
// Two plain kernels (cooperative fusion regressed 4x in round 3 — spill/sync pathology).
// GEMM: one 32x32 tile per 256-thr block, K split 4-ways across waves (13 steps each)
// -> 2048 waves = 2 waves/SIMD TLP + short serial chain; LDS reduce + exp epilogue.

typedef unsigned short u16;
typedef u16   u16x8  __attribute__((ext_vector_type(8)));
typedef u16   u16x4  __attribute__((ext_vector_type(4)));
typedef __bf16 bf16x8 __attribute__((ext_vector_type(8)));
typedef float  f32x4  __attribute__((ext_vector_type(4)));

#define NB 2048
#define NR 256
#define ND 784
#define KC 1664   // 784 + 784 + 96 zero tail; 4 * 416
#define KW 416    // per-wave K slice = 13 steps of 32
#define NSTEP 13

__device__ __forceinline__ u16 f2bf(float f) {
    union { float f; uint32_t u; } v; v.f = f;
    uint32_t r = v.u + 0x7fffu + ((v.u >> 16) & 1u);  // RNE
    return (u16)(r >> 16);
}

// ---------------- prep: build bf16 operand panels ----------------
// blocks 0..511: 4 input rows each (1 wave/row).  blocks 512..575: 4 center rows each.
__global__ __launch_bounds__(256) void prep_kernel(
        const float* __restrict__ inputs, const float* __restrict__ centers,
        const float* __restrict__ sigmas, u16* __restrict__ Acat, u16* __restrict__ Bcat)
{
    const int w    = threadIdx.x >> 6;
    const int lane = threadIdx.x & 63;
    const int blk  = blockIdx.x;
    if (blk < 512) {
        const int b = blk * 4 + w;
        const float4* src = (const float4*)(inputs + (size_t)b * ND);
        float4 v0 = src[lane];
        float4 v1 = src[lane + 64];
        float4 v2 = src[lane + 128];
        float4 v3 = make_float4(0.f, 0.f, 0.f, 0.f);
        if (lane < 4) v3 = src[lane + 192];           // 784 = 4*(64+64+64+4)
        float ss = v0.x*v0.x + v0.y*v0.y + v0.z*v0.z + v0.w*v0.w
                 + v1.x*v1.x + v1.y*v1.y + v1.z*v1.z + v1.w*v1.w
                 + v2.x*v2.x + v2.y*v2.y + v2.z*v2.z + v2.w*v2.w
                 + v3.x*v3.x + v3.y*v3.y + v3.z*v3.z + v3.w*v3.w;
        #pragma unroll
        for (int m = 32; m; m >>= 1) ss += __shfl_xor(ss, m);
        const float inv = rsqrtf(fmaxf(ss, 1e-12f));
        u16* rowA = Acat + (size_t)b * KC;
        auto wrA = [&](int col, float4 v) {
            float x0 = v.x*inv, x1 = v.y*inv, x2 = v.z*inv, x3 = v.w*inv;
            u16x4 q2 = { f2bf(x0*x0), f2bf(x1*x1), f2bf(x2*x2), f2bf(x3*x3) };
            u16x4 q1 = { f2bf(x0),    f2bf(x1),    f2bf(x2),    f2bf(x3)    };
            *(u16x4*)(rowA + col)      = q2;
            *(u16x4*)(rowA + ND + col) = q1;
        };
        wrA(4*lane, v0);
        wrA(4*(lane+64), v1);
        wrA(4*(lane+128), v2);
        if (lane < 4) wrA(4*(lane+192), v3);
        if (lane < 24) {                               // tail cols [1568,1664)
            u16x4 t = {0,0,0,0};
            if (lane == 0) t.x = 0x3F80;               // bf16 1.0
            *(u16x4*)(rowA + 2*ND + 4*lane) = t;
        }
    } else {
        const int r = (blk - 512) * 4 + w;
        const float4* cp = (const float4*)(centers + (size_t)r * ND);
        const float4* sp = (const float4*)(sigmas  + (size_t)r * ND);
        u16* rowB = Bcat + (size_t)r * KC;
        float t3 = 0.f;
        auto wrB = [&](int col, float4 c, float4 s) {
            float w0 = 1.f/(s.x*s.x), w1 = 1.f/(s.y*s.y), w2 = 1.f/(s.z*s.z), w3 = 1.f/(s.w*s.w);
            float c0 = c.x*w0, c1 = c.y*w1, c2 = c.z*w2, c3 = c.w*w3;
            t3 += c.x*c0 + c.y*c1 + c.z*c2 + c.w*c3;
            u16x4 qw = { f2bf(w0), f2bf(w1), f2bf(w2), f2bf(w3) };
            u16x4 qm = { f2bf(-2.f*c0), f2bf(-2.f*c1), f2bf(-2.f*c2), f2bf(-2.f*c3) };
            *(u16x4*)(rowB + col)      = qw;
            *(u16x4*)(rowB + ND + col) = qm;
        };
        wrB(4*lane,       cp[lane],     sp[lane]);
        wrB(4*(lane+64),  cp[lane+64],  sp[lane+64]);
        wrB(4*(lane+128), cp[lane+128], sp[lane+128]);
        if (lane < 4) wrB(4*(lane+192), cp[lane+192], sp[lane+192]);
        #pragma unroll
        for (int m = 32; m; m >>= 1) t3 += __shfl_xor(t3, m);
        if (lane < 24) {
            u16x4 t = {0,0,0,0};
            if (lane == 0) t.x = f2bf(t3);
            *(u16x4*)(rowB + 2*ND + 4*lane) = t;
        }
    }
}

// ---------------- GEMM: 512 blocks x 4 waves; 32x32 tile; K split across waves ------
// Wave w covers K cols [w*416, w*416+416) = 13 steps of 32; PF=4 register pipeline
// (statically indexed).  LDS reduce across waves, then exp + store.
// XCD swizzle (512 % 8 == 0): XCD x reads only A rows [256x, 256x+256).
__global__ __launch_bounds__(256) void rbf_gemm(
        const u16* __restrict__ Acat, const u16* __restrict__ Bcat, float* __restrict__ out)
{
    const int w    = threadIdx.x >> 6;
    const int lane = threadIdx.x & 63;
    const int bid  = (int)blockIdx.x;
    const int xcd  = bid & 7;
    const int j    = bid >> 3;            // 0..63 within XCD
    const int rb   = j >> 3, cb = j & 7;
    const int wm   = xcd * 256 + rb * 32; // batch rows
    const int wn   = cb * 32;             // center rows
    const int r16  = lane & 15;
    const int ko   = (lane >> 4) * 8;
    const int kb   = w * KW;

    const u16* a0p = Acat + (size_t)(wm + r16) * KC + ko + kb;
    const u16* a1p = a0p + 16 * KC;
    const u16* b0p = Bcat + (size_t)(wn + r16) * KC + ko + kb;
    const u16* b1p = b0p + 16 * KC;

    f32x4 acc00 = {0,0,0,0}, acc01 = {0,0,0,0}, acc10 = {0,0,0,0}, acc11 = {0,0,0,0};
    u16x8 a0[4], a1[4], b0[4], b1[4];

#define LDSET(J, KS) do { const int o_ = (KS) * 32;                           \
    a0[J] = *(const u16x8*)(a0p + o_); a1[J] = *(const u16x8*)(a1p + o_);     \
    b0[J] = *(const u16x8*)(b0p + o_); b1[J] = *(const u16x8*)(b1p + o_); } while (0)

#define MM(J) do {                                                                        \
    acc00 = __builtin_amdgcn_mfma_f32_16x16x32_bf16(__builtin_bit_cast(bf16x8, a0[J]),    \
                __builtin_bit_cast(bf16x8, b0[J]), acc00, 0, 0, 0);                       \
    acc01 = __builtin_amdgcn_mfma_f32_16x16x32_bf16(__builtin_bit_cast(bf16x8, a0[J]),    \
                __builtin_bit_cast(bf16x8, b1[J]), acc01, 0, 0, 0);                       \
    acc10 = __builtin_amdgcn_mfma_f32_16x16x32_bf16(__builtin_bit_cast(bf16x8, a1[J]),    \
                __builtin_bit_cast(bf16x8, b0[J]), acc10, 0, 0, 0);                       \
    acc11 = __builtin_amdgcn_mfma_f32_16x16x32_bf16(__builtin_bit_cast(bf16x8, a1[J]),    \
                __builtin_bit_cast(bf16x8, b1[J]), acc11, 0, 0, 0); } while (0)

    #pragma unroll
    for (int s = 0; s < 4; ++s) LDSET(s, s);
    #pragma unroll
    for (int s = 0; s < NSTEP; ++s) {       // fully unrolled: all indices static
        MM(s & 3);
        if (s + 4 < NSTEP) LDSET(s & 3, s + 4);
    }

    // ---- cross-wave K-reduce in LDS + exp + store (layout verified on HW, round 3) ----
    __shared__ float red[4][16][64];
    #pragma unroll
    for (int q = 0; q < 4; ++q) {
        red[w][q     ][lane] = acc00[q];
        red[w][4 + q ][lane] = acc01[q];
        red[w][8 + q ][lane] = acc10[q];
        red[w][12 + q][lane] = acc11[q];
    }
    __syncthreads();
    // wave w owns quadrant w: MO=(w>>1)*16, NO=(w&1)*16
    {
        const int MO = (w >> 1) * 16, NO = (w & 1) * 16;
        const int row0 = wm + MO + ((lane >> 4) << 2);
        const int col  = wn + NO + (lane & 15);
        float* o_ = out + (size_t)row0 * NR + col;
        #pragma unroll
        for (int q = 0; q < 4; ++q) {
            float s = red[0][w*4 + q][lane] + red[1][w*4 + q][lane]
                    + red[2][w*4 + q][lane] + red[3][w*4 + q][lane];
            o_[q * NR] = __expf(-0.5f * s);
        }
    }
#undef LDSET
#undef MM
}

extern "C" void kernel_launch(void* const* d_in, const int* in_sizes, int n_in,
                              void* d_out, int out_size, void* d_ws, size_t ws_size,
                              hipStream_t stream) {
    const float* inputs  = (const float*)d_in[0];
    const float* centers = (const float*)d_in[1];
    const float* sigmas  = (const float*)d_in[2];
    u16* Acat = (u16*)d_ws;                       // 2048*1664*2 = 6.8 MB
    u16* Bcat = Acat + (size_t)NB * KC;           // + 256*1664*2 = 0.85 MB
    prep_kernel<<<576, 256, 0, stream>>>(inputs, centers, sigmas, Acat, Bcat);
    rbf_gemm<<<512, 256, 0, stream>>>(Acat, Bcat, (float*)d_out);
}